// Round 1
// baseline (1641.053 us; speedup 1.0000x reference)
//
#include <hip/hip_runtime.h>

constexpr int N_NODES = 100000;
constexpr int N_EDGES = 1600000;
constexpr int HID = 128;
constexpr int D = 64;
constexpr int T_OUT = 112;

// ---------------------------------------------------------------------------
// Small GEMM: Wcomb[lg][8][64] = W_ee[8][128] @ We[lg][128][64]
//             bcomb[lg][64]    = b_ee[128] @ We[lg] + be[lg]
// grid(4), block(64)
__global__ void wcomb_kernel(const float* __restrict__ W_ee,
                             const float* __restrict__ b_ee,
                             const float* __restrict__ We,
                             const float* __restrict__ be,
                             float* __restrict__ Wcomb,
                             float* __restrict__ bcomb) {
    int lg = blockIdx.x;
    int d = threadIdx.x;
    const float* We_ = We + (size_t)lg * 128 * 64;
    float acc[9];
#pragma unroll
    for (int k = 0; k < 9; ++k) acc[k] = 0.f;
    for (int c = 0; c < 128; ++c) {
        float wv = We_[c * 64 + d];
#pragma unroll
        for (int k = 0; k < 8; ++k) acc[k] += W_ee[k * 128 + c] * wv;
        acc[8] += b_ee[c] * wv;
    }
#pragma unroll
    for (int k = 0; k < 8; ++k) Wcomb[lg * 512 + k * 64 + d] = acc[k];
    bcomb[lg * 64 + d] = acc[8] + be[lg * 64 + d];
}

// ---------------------------------------------------------------------------
// Encoder: h = [node_features[node_index], x@W_oh+b_oh] @ W_ne + b_ne
// split into A = h[:, :64], B = h[:, 64:]. One wave per node, lane = channel d.
__global__ __launch_bounds__(256) void encoder_kernel(
    const float* __restrict__ x, const int* __restrict__ node_index,
    const float* __restrict__ node_features,
    const float* __restrict__ W_oh, const float* __restrict__ b_oh,
    const float* __restrict__ W_ne, const float* __restrict__ b_ne,
    float* __restrict__ A, float* __restrict__ B) {
    int tid = threadIdx.x;
    int w = tid >> 6, d = tid & 63;
    int n = blockIdx.x * 4 + w;

    float xf[8];
    const float* xr = x + (size_t)n * 8;
#pragma unroll
    for (int j = 0; j < 8; ++j) xf[j] = xr[j];

    float nf[16];
    int ni = node_index[n];
    const float* nfr = node_features + (size_t)ni * 8;
#pragma unroll
    for (int k = 0; k < 8; ++k) nf[k] = nfr[k];
#pragma unroll
    for (int k = 0; k < 8; ++k) {
        float acc = b_oh[k];
#pragma unroll
        for (int j = 0; j < 8; ++j) acc += xf[j] * W_oh[j * 8 + k];
        nf[8 + k] = acc;
    }
    float hA = b_ne[d], hB = b_ne[64 + d];
#pragma unroll
    for (int k = 0; k < 16; ++k) {
        hA += nf[k] * W_ne[k * 128 + d];
        hB += nf[k] * W_ne[k * 128 + 64 + d];
    }
    A[(size_t)n * 64 + d] = hA;
    B[(size_t)n * 64 + d] = hB;
}

// ---------------------------------------------------------------------------
// CSR build
__global__ void hist_kernel(const int* __restrict__ edge_index, int* __restrict__ deg) {
    int e = blockIdx.x * 256 + threadIdx.x;
    if (e < N_EDGES) atomicAdd(&deg[edge_index[N_EDGES + e]], 1);
}

// Single-block exclusive scan of deg[N] -> rowptr[N+1], pos[N] (cursor copy)
__global__ __launch_bounds__(1024) void scan_kernel(const int* __restrict__ deg,
                                                    int* __restrict__ rowptr,
                                                    int* __restrict__ pos) {
    __shared__ int lds[1024];
    int t = threadIdx.x;
    const int C = (N_NODES + 1023) / 1024;  // 98
    int lo = t * C;
    int hi = lo + C < N_NODES ? lo + C : N_NODES;
    int s = 0;
    for (int i = lo; i < hi; ++i) s += deg[i];
    lds[t] = s;
    __syncthreads();
    // Hillis-Steele inclusive scan
    for (int offd = 1; offd < 1024; offd <<= 1) {
        int v = (t >= offd) ? lds[t - offd] : 0;
        __syncthreads();
        lds[t] += v;
        __syncthreads();
    }
    int prefix = (t == 0) ? 0 : lds[t - 1];
    for (int i = lo; i < hi; ++i) {
        rowptr[i] = prefix;
        pos[i] = prefix;
        prefix += deg[i];
    }
    if (t == 1023) rowptr[N_NODES] = lds[1023];
}

// Scatter edges into dst-sorted order; permute src + edge_attr along with them.
__global__ void scatter_kernel(const int* __restrict__ edge_index,
                               const float* __restrict__ edge_attr,
                               int* __restrict__ pos,
                               int* __restrict__ src_perm,
                               float* __restrict__ ea_perm) {
    int e = blockIdx.x * 256 + threadIdx.x;
    if (e >= N_EDGES) return;
    int dn = edge_index[N_EDGES + e];
    int idx = atomicAdd(&pos[dn], 1);
    src_perm[idx] = edge_index[e];
    const float4* s4 = (const float4*)(edge_attr + (size_t)e * 8);
    float4* d4 = (float4*)(ea_perm + (size_t)idx * 8);
    d4[0] = s4[0];
    d4[1] = s4[1];
}

// ---------------------------------------------------------------------------
// hl = relu(LayerNorm(Y) * g + b), per-node LN over 64 channels.
__global__ __launch_bounds__(256) void ln_relu_kernel(const float* __restrict__ Y,
                                                      const float* __restrict__ g,
                                                      const float* __restrict__ b,
                                                      float* __restrict__ hl) {
    int tid = threadIdx.x;
    int w = tid >> 6, d = tid & 63;
    int n = blockIdx.x * 4 + w;
    float y = Y[(size_t)n * 64 + d];
    float s = y, sq = y * y;
#pragma unroll
    for (int offd = 32; offd >= 1; offd >>= 1) {
        s += __shfl_xor(s, offd, 64);
        sq += __shfl_xor(sq, offd, 64);
    }
    float mean = s * (1.f / 64.f);
    float var = sq * (1.f / 64.f) - mean * mean;
    float rs = rsqrtf(var + 1e-5f);
    float h = (y - mean) * rs * g[d] + b[d];
    hl[(size_t)n * 64 + d] = fmaxf(h, 0.f);
}

// ---------------------------------------------------------------------------
// Fused: softmax-aggregation over incoming edges (CSR gather, one wave/node)
// + epilogue (hl + agg) @ Wm + bm, accumulated into Y (reversible residual).
__global__ __launch_bounds__(256) void agg_epi_kernel(
    const float* __restrict__ hl, float* __restrict__ Y,
    const int* __restrict__ rowptr, const int* __restrict__ src_perm,
    const float* __restrict__ ea_perm,
    const float* __restrict__ Wcomb, const float* __restrict__ bcomb,
    const float* __restrict__ Wm, const float* __restrict__ bm) {
    __shared__ float s_wc[512];
    __shared__ float s_wm[4096];
    __shared__ float s_v[256];
    int tid = threadIdx.x;
    for (int i = tid; i < 512; i += 256) s_wc[i] = Wcomb[i];
    for (int i = tid; i < 4096; i += 256) s_wm[i] = Wm[i];
    __syncthreads();

    int w = tid >> 6, d = tid & 63;
    int n = blockIdx.x * 4 + w;
    float bc = bcomb[d];
    float num = 0.f, den = 0.f;
    int start = rowptr[n], end = rowptr[n + 1];
    for (int i = start; i < end; ++i) {
        int s = src_perm[i];
        const float4* ea4 = (const float4*)(ea_perm + (size_t)i * 8);
        float4 a0 = ea4[0];
        float4 a1 = ea4[1];
        float eW = bc;
        eW += a0.x * s_wc[d];
        eW += a0.y * s_wc[64 + d];
        eW += a0.z * s_wc[128 + d];
        eW += a0.w * s_wc[192 + d];
        eW += a1.x * s_wc[256 + d];
        eW += a1.y * s_wc[320 + d];
        eW += a1.z * s_wc[384 + d];
        eW += a1.w * s_wc[448 + d];
        float m = hl[(size_t)s * 64 + d] + eW;
        m = fmaxf(m, 0.f) + 1e-7f;
        float ex = __expf(m);  // softmax is shift-invariant; msg bounded -> no max needed
        den += ex;
        num += ex * m;
    }
    float agg = num / (den + 1e-16f);
    float v = hl[(size_t)n * 64 + d] + agg;
    s_v[w * 64 + d] = v;  // wave-local: no block barrier needed
    float acc = bm[d];
    for (int k = 0; k < 64; ++k) acc += s_v[w * 64 + k] * s_wm[k * 64 + d];
    Y[(size_t)n * 64 + d] += acc;
}

// ---------------------------------------------------------------------------
// Final: LN over 128 -> relu -> @Wp + bp. One wave per node.
__global__ __launch_bounds__(256) void final_kernel(
    const float* __restrict__ A, const float* __restrict__ B,
    const float* __restrict__ lg, const float* __restrict__ lb,
    const float* __restrict__ Wp, const float* __restrict__ bp,
    float* __restrict__ out) {
    __shared__ float s_v[4][128];
    int tid = threadIdx.x;
    int w = tid >> 6, d = tid & 63;
    int n = blockIdx.x * 4 + w;
    float v0 = A[(size_t)n * 64 + d];
    float v1 = B[(size_t)n * 64 + d];
    float s = v0 + v1, sq = v0 * v0 + v1 * v1;
#pragma unroll
    for (int offd = 32; offd >= 1; offd >>= 1) {
        s += __shfl_xor(s, offd, 64);
        sq += __shfl_xor(sq, offd, 64);
    }
    float mean = s * (1.f / 128.f);
    float var = sq * (1.f / 128.f) - mean * mean;
    float rs = rsqrtf(var + 1e-5f);
    float r0 = fmaxf((v0 - mean) * rs * lg[d] + lb[d], 0.f);
    float r1 = fmaxf((v1 - mean) * rs * lg[64 + d] + lb[64 + d], 0.f);
    s_v[w][d] = r0;
    s_v[w][64 + d] = r1;  // wave-local
    for (int t = d; t < T_OUT; t += 64) {
        float acc = bp[t];
        for (int c = 0; c < 128; ++c) acc += s_v[w][c] * Wp[c * T_OUT + t];
        out[(size_t)n * T_OUT + t] = acc;
    }
}

// ---------------------------------------------------------------------------
extern "C" void kernel_launch(void* const* d_in, const int* in_sizes, int n_in,
                              void* d_out, int out_size, void* d_ws, size_t ws_size,
                              hipStream_t stream) {
    const float* x            = (const float*)d_in[0];
    const int* node_index     = (const int*)d_in[1];
    const int* edge_index     = (const int*)d_in[2];
    const float* edge_attr    = (const float*)d_in[3];
    const float* node_features= (const float*)d_in[4];
    const float* W_oh         = (const float*)d_in[5];
    const float* b_oh         = (const float*)d_in[6];
    const float* W_ne         = (const float*)d_in[7];
    const float* b_ne         = (const float*)d_in[8];
    const float* W_ee         = (const float*)d_in[9];
    const float* b_ee         = (const float*)d_in[10];
    const float* ln_g         = (const float*)d_in[11];
    const float* ln_b         = (const float*)d_in[12];
    const float* We           = (const float*)d_in[13];
    const float* be           = (const float*)d_in[14];
    const float* Wm           = (const float*)d_in[15];
    const float* bm           = (const float*)d_in[16];
    const float* last_g       = (const float*)d_in[17];
    const float* last_b       = (const float*)d_in[18];
    const float* Wp           = (const float*)d_in[19];
    const float* bp           = (const float*)d_in[20];
    float* out = (float*)d_out;

    char* ws = (char*)d_ws;
    size_t off = 0;
    auto alloc = [&](size_t bytes) -> void* {
        void* p = ws + off;
        off = (off + bytes + 255) & ~(size_t)255;
        return p;
    };
    float* A        = (float*)alloc((size_t)N_NODES * 64 * 4);
    float* B        = (float*)alloc((size_t)N_NODES * 64 * 4);
    float* hl       = (float*)alloc((size_t)N_NODES * 64 * 4);
    int* deg        = (int*)alloc((size_t)N_NODES * 4);
    int* rowptr     = (int*)alloc((size_t)(N_NODES + 1) * 4);
    int* pos        = (int*)alloc((size_t)N_NODES * 4);
    int* src_perm   = (int*)alloc((size_t)N_EDGES * 4);
    float* ea_perm  = (float*)alloc((size_t)N_EDGES * 8 * 4);
    float* Wcomb    = (float*)alloc(4 * 512 * 4);
    float* bcomb    = (float*)alloc(4 * 64 * 4);
    (void)ws_size; (void)in_sizes; (void)n_in; (void)out_size;

    const int NB_NODE = N_NODES / 4;            // 25000 (N divisible by 4)
    const int NB_EDGE = (N_EDGES + 255) / 256;  // 6250

    hipMemsetAsync(deg, 0, (size_t)N_NODES * 4, stream);
    wcomb_kernel<<<4, 64, 0, stream>>>(W_ee, b_ee, We, be, Wcomb, bcomb);
    encoder_kernel<<<NB_NODE, 256, 0, stream>>>(x, node_index, node_features,
                                                W_oh, b_oh, W_ne, b_ne, A, B);
    hist_kernel<<<NB_EDGE, 256, 0, stream>>>(edge_index, deg);
    scan_kernel<<<1, 1024, 0, stream>>>(deg, rowptr, pos);
    scatter_kernel<<<NB_EDGE, 256, 0, stream>>>(edge_index, edge_attr, pos,
                                                src_perm, ea_perm);

    for (int lg = 0; lg < 4; ++lg) {
        const float* Yin = (lg & 1) ? A : B;
        float* Yout      = (lg & 1) ? B : A;
        ln_relu_kernel<<<NB_NODE, 256, 0, stream>>>(Yin, ln_g + lg * 64,
                                                    ln_b + lg * 64, hl);
        agg_epi_kernel<<<NB_NODE, 256, 0, stream>>>(
            hl, Yout, rowptr, src_perm, ea_perm,
            Wcomb + lg * 512, bcomb + lg * 64,
            Wm + (size_t)lg * 4096, bm + lg * 64);
    }

    final_kernel<<<NB_NODE, 256, 0, stream>>>(A, B, last_g, last_b, Wp, bp, out);
}

// Round 2
// 1292.521 us; speedup vs baseline: 1.2697x; 1.2697x over previous
//
#include <hip/hip_runtime.h>

constexpr int N_NODES = 100000;
constexpr int N_EDGES = 1600000;
constexpr int HID = 128;
constexpr int D = 64;
constexpr int T_OUT = 112;

// ---------------------------------------------------------------------------
// Small GEMM: Wcomb[lg][8][64] = W_ee[8][128] @ We[lg][128][64]
//             bcomb[lg][64]    = b_ee[128] @ We[lg] + be[lg]
// grid(4), block(64)
__global__ void wcomb_kernel(const float* __restrict__ W_ee,
                             const float* __restrict__ b_ee,
                             const float* __restrict__ We,
                             const float* __restrict__ be,
                             float* __restrict__ Wcomb,
                             float* __restrict__ bcomb) {
    int lg = blockIdx.x;
    int d = threadIdx.x;
    const float* We_ = We + (size_t)lg * 128 * 64;
    float acc[9];
#pragma unroll
    for (int k = 0; k < 9; ++k) acc[k] = 0.f;
    for (int c = 0; c < 128; ++c) {
        float wv = We_[c * 64 + d];
#pragma unroll
        for (int k = 0; k < 8; ++k) acc[k] += W_ee[k * 128 + c] * wv;
        acc[8] += b_ee[c] * wv;
    }
#pragma unroll
    for (int k = 0; k < 8; ++k) Wcomb[lg * 512 + k * 64 + d] = acc[k];
    bcomb[lg * 64 + d] = acc[8] + be[lg * 64 + d];
}

// ---------------------------------------------------------------------------
// Encoder: h = [node_features[node_index], x@W_oh+b_oh] @ W_ne + b_ne
// split into A = h[:, :64], B = h[:, 64:]. One wave per node, lane = channel d.
__global__ __launch_bounds__(256) void encoder_kernel(
    const float* __restrict__ x, const int* __restrict__ node_index,
    const float* __restrict__ node_features,
    const float* __restrict__ W_oh, const float* __restrict__ b_oh,
    const float* __restrict__ W_ne, const float* __restrict__ b_ne,
    float* __restrict__ A, float* __restrict__ B) {
    int tid = threadIdx.x;
    int w = tid >> 6, d = tid & 63;
    int n = blockIdx.x * 4 + w;

    float xf[8];
    const float* xr = x + (size_t)n * 8;
#pragma unroll
    for (int j = 0; j < 8; ++j) xf[j] = xr[j];

    float nf[16];
    int ni = node_index[n];
    const float* nfr = node_features + (size_t)ni * 8;
#pragma unroll
    for (int k = 0; k < 8; ++k) nf[k] = nfr[k];
#pragma unroll
    for (int k = 0; k < 8; ++k) {
        float acc = b_oh[k];
#pragma unroll
        for (int j = 0; j < 8; ++j) acc += xf[j] * W_oh[j * 8 + k];
        nf[8 + k] = acc;
    }
    float hA = b_ne[d], hB = b_ne[64 + d];
#pragma unroll
    for (int k = 0; k < 16; ++k) {
        hA += nf[k] * W_ne[k * 128 + d];
        hB += nf[k] * W_ne[k * 128 + 64 + d];
    }
    A[(size_t)n * 64 + d] = hA;
    B[(size_t)n * 64 + d] = hB;
}

// ---------------------------------------------------------------------------
// CSR build
__global__ void hist_kernel(const int* __restrict__ edge_index, int* __restrict__ deg) {
    int e = blockIdx.x * 256 + threadIdx.x;
    if (e < N_EDGES) atomicAdd(&deg[edge_index[N_EDGES + e]], 1);
}

// Single-block exclusive scan of deg[N] -> rowptr[N+1], pos[N] (cursor copy)
__global__ __launch_bounds__(1024) void scan_kernel(const int* __restrict__ deg,
                                                    int* __restrict__ rowptr,
                                                    int* __restrict__ pos) {
    __shared__ int lds[1024];
    int t = threadIdx.x;
    const int C = (N_NODES + 1023) / 1024;  // 98
    int lo = t * C;
    int hi = lo + C < N_NODES ? lo + C : N_NODES;
    int s = 0;
    for (int i = lo; i < hi; ++i) s += deg[i];
    lds[t] = s;
    __syncthreads();
    // Hillis-Steele inclusive scan
    for (int offd = 1; offd < 1024; offd <<= 1) {
        int v = (t >= offd) ? lds[t - offd] : 0;
        __syncthreads();
        lds[t] += v;
        __syncthreads();
    }
    int prefix = (t == 0) ? 0 : lds[t - 1];
    for (int i = lo; i < hi; ++i) {
        rowptr[i] = prefix;
        pos[i] = prefix;
        prefix += deg[i];
    }
    if (t == 1023) rowptr[N_NODES] = lds[1023];
}

// Scatter edges into dst-sorted order; permute src + edge_attr along with them.
__global__ void scatter_kernel(const int* __restrict__ edge_index,
                               const float* __restrict__ edge_attr,
                               int* __restrict__ pos,
                               int* __restrict__ src_perm,
                               float* __restrict__ ea_perm) {
    int e = blockIdx.x * 256 + threadIdx.x;
    if (e >= N_EDGES) return;
    int dn = edge_index[N_EDGES + e];
    int idx = atomicAdd(&pos[dn], 1);
    src_perm[idx] = edge_index[e];
    const float4* s4 = (const float4*)(edge_attr + (size_t)e * 8);
    float4* d4 = (float4*)(ea_perm + (size_t)idx * 8);
    d4[0] = s4[0];
    d4[1] = s4[1];
}

// ---------------------------------------------------------------------------
// hl = relu(LayerNorm(Y) * g + b), per-node LN over 64 channels.
__global__ __launch_bounds__(256) void ln_relu_kernel(const float* __restrict__ Y,
                                                      const float* __restrict__ g,
                                                      const float* __restrict__ b,
                                                      float* __restrict__ hl) {
    int tid = threadIdx.x;
    int w = tid >> 6, d = tid & 63;
    int n = blockIdx.x * 4 + w;
    float y = Y[(size_t)n * 64 + d];
    float s = y, sq = y * y;
#pragma unroll
    for (int offd = 32; offd >= 1; offd >>= 1) {
        s += __shfl_xor(s, offd, 64);
        sq += __shfl_xor(sq, offd, 64);
    }
    float mean = s * (1.f / 64.f);
    float var = sq * (1.f / 64.f) - mean * mean;
    float rs = rsqrtf(var + 1e-5f);
    float h = (y - mean) * rs * g[d] + b[d];
    hl[(size_t)n * 64 + d] = fmaxf(h, 0.f);
}

// ---------------------------------------------------------------------------
// Fused: softmax-aggregation over incoming edges (CSR gather, one wave/node)
// + epilogue (hl + agg) @ Wm + bm, accumulated into Y (reversible residual).
// Edge loop unrolled x4 with batched loads: 4 independent hl-gathers +
// 8 float4 ea loads in flight per iteration (latency fix — was 1 gather/iter).
__global__ __launch_bounds__(256) void agg_epi_kernel(
    const float* __restrict__ hl, float* __restrict__ Y,
    const int* __restrict__ rowptr, const int* __restrict__ src_perm,
    const float* __restrict__ ea_perm,
    const float* __restrict__ Wcomb, const float* __restrict__ bcomb,
    const float* __restrict__ Wm, const float* __restrict__ bm) {
    __shared__ float s_wc[512];
    __shared__ float s_wm[4096];
    __shared__ float s_v[256];
    int tid = threadIdx.x;
    for (int i = tid; i < 512; i += 256) s_wc[i] = Wcomb[i];
    for (int i = tid; i < 4096; i += 256) s_wm[i] = Wm[i];
    __syncthreads();

    int w = tid >> 6, d = tid & 63;
    int n = blockIdx.x * 4 + w;

    // hoist the per-lane Wcomb column into registers (loop-invariant)
    float wc[8];
#pragma unroll
    for (int k = 0; k < 8; ++k) wc[k] = s_wc[k * 64 + d];
    float bc = bcomb[d];

    float num = 0.f, den = 0.f;
    int start = rowptr[n], end = rowptr[n + 1];
    const float4* e4 = (const float4*)ea_perm;

    int i = start;
    for (; i + 4 <= end; i += 4) {
        // issue the 4 random gathers first (critical-path loads)
        int s0 = src_perm[i + 0];
        int s1 = src_perm[i + 1];
        int s2 = src_perm[i + 2];
        int s3 = src_perm[i + 3];
        float h0 = hl[(size_t)s0 * 64 + d];
        float h1 = hl[(size_t)s1 * 64 + d];
        float h2 = hl[(size_t)s2 * 64 + d];
        float h3 = hl[(size_t)s3 * 64 + d];
        // coalesced edge-attr loads (8 x float4)
        float4 a0 = e4[(size_t)(i + 0) * 2 + 0], a1 = e4[(size_t)(i + 0) * 2 + 1];
        float4 b0 = e4[(size_t)(i + 1) * 2 + 0], b1 = e4[(size_t)(i + 1) * 2 + 1];
        float4 c0 = e4[(size_t)(i + 2) * 2 + 0], c1 = e4[(size_t)(i + 2) * 2 + 1];
        float4 d0 = e4[(size_t)(i + 3) * 2 + 0], d1 = e4[(size_t)(i + 3) * 2 + 1];
#define DOT8(A0, A1) (bc + A0.x * wc[0] + A0.y * wc[1] + A0.z * wc[2] + A0.w * wc[3] \
                         + A1.x * wc[4] + A1.y * wc[5] + A1.z * wc[6] + A1.w * wc[7])
        float m0 = fmaxf(h0 + DOT8(a0, a1), 0.f) + 1e-7f;
        float m1 = fmaxf(h1 + DOT8(b0, b1), 0.f) + 1e-7f;
        float m2 = fmaxf(h2 + DOT8(c0, c1), 0.f) + 1e-7f;
        float m3 = fmaxf(h3 + DOT8(d0, d1), 0.f) + 1e-7f;
        float x0 = __expf(m0), x1 = __expf(m1), x2 = __expf(m2), x3 = __expf(m3);
        den += x0; num += x0 * m0;
        den += x1; num += x1 * m1;
        den += x2; num += x2 * m2;
        den += x3; num += x3 * m3;
    }
    for (; i < end; ++i) {
        int s = src_perm[i];
        float4 a0 = e4[(size_t)i * 2 + 0], a1 = e4[(size_t)i * 2 + 1];
        float h = hl[(size_t)s * 64 + d];
        float m = fmaxf(h + DOT8(a0, a1), 0.f) + 1e-7f;
        float ex = __expf(m);
        den += ex; num += ex * m;
    }
#undef DOT8

    float agg = num / (den + 1e-16f);
    float v = hl[(size_t)n * 64 + d] + agg;
    s_v[w * 64 + d] = v;  // wave-local: no block barrier needed
    float acc = bm[d];
    for (int k = 0; k < 64; ++k) acc += s_v[w * 64 + k] * s_wm[k * 64 + d];
    Y[(size_t)n * 64 + d] += acc;
}

// ---------------------------------------------------------------------------
// Final: LN over 128 -> relu -> @Wp + bp. 512 threads = 8 nodes per block;
// Wp staged in LDS ONCE per block (was: streamed from L1/L2 per wave,
// ~8.5 GB of L2 traffic). Each lane computes outputs t=d and t=d+64.
__global__ __launch_bounds__(512) void final_kernel(
    const float* __restrict__ A, const float* __restrict__ B,
    const float* __restrict__ lg, const float* __restrict__ lb,
    const float* __restrict__ Wp, const float* __restrict__ bp,
    float* __restrict__ out) {
    __shared__ float s_wp[128 * 112 + 64];  // +64 pad: dummy reads for t1>=112
    __shared__ float s_h[8][128];
    int tid = threadIdx.x;
    for (int i = tid; i < 128 * 112; i += 512) s_wp[i] = Wp[i];
    if (tid < 64) s_wp[128 * 112 + tid] = 0.f;

    int w = tid >> 6, d = tid & 63;
    int n = blockIdx.x * 8 + w;
    float v0 = A[(size_t)n * 64 + d];
    float v1 = B[(size_t)n * 64 + d];
    float s = v0 + v1, sq = v0 * v0 + v1 * v1;
#pragma unroll
    for (int offd = 32; offd >= 1; offd >>= 1) {
        s += __shfl_xor(s, offd, 64);
        sq += __shfl_xor(sq, offd, 64);
    }
    float mean = s * (1.f / 128.f);
    float var = sq * (1.f / 128.f) - mean * mean;
    float rs = rsqrtf(var + 1e-5f);
    float r0 = fmaxf((v0 - mean) * rs * lg[d] + lb[d], 0.f);
    float r1 = fmaxf((v1 - mean) * rs * lg[64 + d] + lb[64 + d], 0.f);
    s_h[w][d] = r0;
    s_h[w][64 + d] = r1;
    __syncthreads();  // covers s_wp (s_h is wave-local)

    int t0 = d, t1 = d + 64;
    float acc0 = bp[t0];
    float acc1 = (t1 < T_OUT) ? bp[t1] : 0.f;
#pragma unroll 4
    for (int c = 0; c < 128; ++c) {
        float hv = s_h[w][c];                 // broadcast (conflict-free)
        acc0 += hv * s_wp[c * T_OUT + t0];    // stride-1 across lanes
        acc1 += hv * s_wp[c * T_OUT + t1];    // pad-read for t1>=112
    }
    out[(size_t)n * T_OUT + t0] = acc0;
    if (t1 < T_OUT) out[(size_t)n * T_OUT + t1] = acc1;
}

// ---------------------------------------------------------------------------
extern "C" void kernel_launch(void* const* d_in, const int* in_sizes, int n_in,
                              void* d_out, int out_size, void* d_ws, size_t ws_size,
                              hipStream_t stream) {
    const float* x            = (const float*)d_in[0];
    const int* node_index     = (const int*)d_in[1];
    const int* edge_index     = (const int*)d_in[2];
    const float* edge_attr    = (const float*)d_in[3];
    const float* node_features= (const float*)d_in[4];
    const float* W_oh         = (const float*)d_in[5];
    const float* b_oh         = (const float*)d_in[6];
    const float* W_ne         = (const float*)d_in[7];
    const float* b_ne         = (const float*)d_in[8];
    const float* W_ee         = (const float*)d_in[9];
    const float* b_ee         = (const float*)d_in[10];
    const float* ln_g         = (const float*)d_in[11];
    const float* ln_b         = (const float*)d_in[12];
    const float* We           = (const float*)d_in[13];
    const float* be           = (const float*)d_in[14];
    const float* Wm           = (const float*)d_in[15];
    const float* bm           = (const float*)d_in[16];
    const float* last_g       = (const float*)d_in[17];
    const float* last_b       = (const float*)d_in[18];
    const float* Wp           = (const float*)d_in[19];
    const float* bp           = (const float*)d_in[20];
    float* out = (float*)d_out;

    char* ws = (char*)d_ws;
    size_t off = 0;
    auto alloc = [&](size_t bytes) -> void* {
        void* p = ws + off;
        off = (off + bytes + 255) & ~(size_t)255;
        return p;
    };
    float* A        = (float*)alloc((size_t)N_NODES * 64 * 4);
    float* B        = (float*)alloc((size_t)N_NODES * 64 * 4);
    float* hl       = (float*)alloc((size_t)N_NODES * 64 * 4);
    int* deg        = (int*)alloc((size_t)N_NODES * 4);
    int* rowptr     = (int*)alloc((size_t)(N_NODES + 1) * 4);
    int* pos        = (int*)alloc((size_t)N_NODES * 4);
    int* src_perm   = (int*)alloc((size_t)N_EDGES * 4);
    float* ea_perm  = (float*)alloc((size_t)N_EDGES * 8 * 4);
    float* Wcomb    = (float*)alloc(4 * 512 * 4);
    float* bcomb    = (float*)alloc(4 * 64 * 4);
    (void)ws_size; (void)in_sizes; (void)n_in; (void)out_size;

    const int NB_NODE = N_NODES / 4;            // 25000 (N divisible by 4)
    const int NB_EDGE = (N_EDGES + 255) / 256;  // 6250

    hipMemsetAsync(deg, 0, (size_t)N_NODES * 4, stream);
    wcomb_kernel<<<4, 64, 0, stream>>>(W_ee, b_ee, We, be, Wcomb, bcomb);
    encoder_kernel<<<NB_NODE, 256, 0, stream>>>(x, node_index, node_features,
                                                W_oh, b_oh, W_ne, b_ne, A, B);
    hist_kernel<<<NB_EDGE, 256, 0, stream>>>(edge_index, deg);
    scan_kernel<<<1, 1024, 0, stream>>>(deg, rowptr, pos);
    scatter_kernel<<<NB_EDGE, 256, 0, stream>>>(edge_index, edge_attr, pos,
                                                src_perm, ea_perm);

    for (int lg = 0; lg < 4; ++lg) {
        const float* Yin = (lg & 1) ? A : B;
        float* Yout      = (lg & 1) ? B : A;
        ln_relu_kernel<<<NB_NODE, 256, 0, stream>>>(Yin, ln_g + lg * 64,
                                                    ln_b + lg * 64, hl);
        agg_epi_kernel<<<NB_NODE, 256, 0, stream>>>(
            hl, Yout, rowptr, src_perm, ea_perm,
            Wcomb + lg * 512, bcomb + lg * 64,
            Wm + (size_t)lg * 4096, bm + lg * 64);
    }

    final_kernel<<<N_NODES / 8, 512, 0, stream>>>(A, B, last_g, last_b, Wp, bp, out);
}

// Round 3
// 1081.327 us; speedup vs baseline: 1.5176x; 1.1953x over previous
//
#include <hip/hip_runtime.h>

constexpr int N_NODES = 100000;
constexpr int N_EDGES = 1600000;
constexpr int HID = 128;
constexpr int D = 64;
constexpr int T_OUT = 112;

constexpr int SCAN_CHUNK = 1024;                                  // elems per block
constexpr int SCAN_BLOCKS = (N_NODES + SCAN_CHUNK - 1) / SCAN_CHUNK;  // 98

// ---------------------------------------------------------------------------
// Small GEMM: Wcomb[lg][8][64] = W_ee[8][128] @ We[lg][128][64]
//             bcomb[lg][64]    = b_ee[128] @ We[lg] + be[lg]
__global__ void wcomb_kernel(const float* __restrict__ W_ee,
                             const float* __restrict__ b_ee,
                             const float* __restrict__ We,
                             const float* __restrict__ be,
                             float* __restrict__ Wcomb,
                             float* __restrict__ bcomb) {
    int lg = blockIdx.x;
    int d = threadIdx.x;
    const float* We_ = We + (size_t)lg * 128 * 64;
    float acc[9];
#pragma unroll
    for (int k = 0; k < 9; ++k) acc[k] = 0.f;
    for (int c = 0; c < 128; ++c) {
        float wv = We_[c * 64 + d];
#pragma unroll
        for (int k = 0; k < 8; ++k) acc[k] += W_ee[k * 128 + c] * wv;
        acc[8] += b_ee[c] * wv;
    }
#pragma unroll
    for (int k = 0; k < 8; ++k) Wcomb[lg * 512 + k * 64 + d] = acc[k];
    bcomb[lg * 64 + d] = acc[8] + be[lg * 64 + d];
}

// ---------------------------------------------------------------------------
// Encoder: h = [node_features[node_index], x@W_oh+b_oh] @ W_ne + b_ne
__global__ __launch_bounds__(256) void encoder_kernel(
    const float* __restrict__ x, const int* __restrict__ node_index,
    const float* __restrict__ node_features,
    const float* __restrict__ W_oh, const float* __restrict__ b_oh,
    const float* __restrict__ W_ne, const float* __restrict__ b_ne,
    float* __restrict__ A, float* __restrict__ B) {
    int tid = threadIdx.x;
    int w = tid >> 6, d = tid & 63;
    int n = blockIdx.x * 4 + w;

    float xf[8];
    const float* xr = x + (size_t)n * 8;
#pragma unroll
    for (int j = 0; j < 8; ++j) xf[j] = xr[j];

    float nf[16];
    int ni = node_index[n];
    const float* nfr = node_features + (size_t)ni * 8;
#pragma unroll
    for (int k = 0; k < 8; ++k) nf[k] = nfr[k];
#pragma unroll
    for (int k = 0; k < 8; ++k) {
        float acc = b_oh[k];
#pragma unroll
        for (int j = 0; j < 8; ++j) acc += xf[j] * W_oh[j * 8 + k];
        nf[8 + k] = acc;
    }
    float hA = b_ne[d], hB = b_ne[64 + d];
#pragma unroll
    for (int k = 0; k < 16; ++k) {
        hA += nf[k] * W_ne[k * 128 + d];
        hB += nf[k] * W_ne[k * 128 + 64 + d];
    }
    A[(size_t)n * 64 + d] = hA;
    B[(size_t)n * 64 + d] = hB;
}

// ---------------------------------------------------------------------------
// CSR build
__global__ void hist_kernel(const int* __restrict__ edge_index, int* __restrict__ deg) {
    int e = blockIdx.x * 256 + threadIdx.x;
    if (e < N_EDGES) atomicAdd(&deg[edge_index[N_EDGES + e]], 1);
}

// --- multi-block scan, phase 1: per-block sums (coalesced int4 loads) ------
__global__ __launch_bounds__(256) void block_sum_kernel(const int* __restrict__ deg,
                                                        int* __restrict__ blocksum) {
    __shared__ int s_w[4];
    int t = threadIdx.x;
    int base = blockIdx.x * SCAN_CHUNK + t * 4;
    int s = 0;
    if (base + 3 < N_NODES) {
        int4 v = *(const int4*)(deg + base);
        s = v.x + v.y + v.z + v.w;
    } else {
        for (int j = 0; j < 4; ++j)
            if (base + j < N_NODES) s += deg[base + j];
    }
#pragma unroll
    for (int o = 32; o >= 1; o >>= 1) s += __shfl_xor(s, o, 64);
    if ((t & 63) == 0) s_w[t >> 6] = s;
    __syncthreads();
    if (t == 0) blocksum[blockIdx.x] = s_w[0] + s_w[1] + s_w[2] + s_w[3];
}

// --- phase 2: one wave scans the 98 block sums -> exclusive offsets --------
__global__ __launch_bounds__(64) void scan_sums_kernel(const int* __restrict__ blocksum,
                                                       int* __restrict__ blockoff,
                                                       int* __restrict__ rowptr) {
    int t = threadIdx.x;  // 64 lanes, each owns 2 consecutive sums
    int i0 = 2 * t, i1 = 2 * t + 1;
    int v0 = (i0 < SCAN_BLOCKS) ? blocksum[i0] : 0;
    int v1 = (i1 < SCAN_BLOCKS) ? blocksum[i1] : 0;
    int s = v0 + v1;
    int incl = s;
#pragma unroll
    for (int o = 1; o < 64; o <<= 1) {
        int u = __shfl_up(incl, o, 64);
        if (t >= o) incl += u;
    }
    int excl = incl - s;
    if (i0 < SCAN_BLOCKS) blockoff[i0] = excl;
    if (i1 < SCAN_BLOCKS) blockoff[i1] = excl + v0;
    if (t == 63) rowptr[N_NODES] = incl;  // grand total
}

// --- phase 3: in-block scan + emit rowptr/pos (coalesced int4 I/O) ---------
__global__ __launch_bounds__(256) void emit_kernel(const int* __restrict__ deg,
                                                   const int* __restrict__ blockoff,
                                                   int* __restrict__ rowptr,
                                                   int* __restrict__ pos) {
    __shared__ int s_w[4];
    int t = threadIdx.x;
    int w = t >> 6, lane = t & 63;
    int base = blockIdx.x * SCAN_CHUNK + t * 4;

    int d0 = 0, d1 = 0, d2 = 0, d3 = 0;
    if (base + 3 < N_NODES) {
        int4 v = *(const int4*)(deg + base);
        d0 = v.x; d1 = v.y; d2 = v.z; d3 = v.w;
    } else {
        if (base + 0 < N_NODES) d0 = deg[base + 0];
        if (base + 1 < N_NODES) d1 = deg[base + 1];
        if (base + 2 < N_NODES) d2 = deg[base + 2];
        if (base + 3 < N_NODES) d3 = deg[base + 3];
    }
    int s = d0 + d1 + d2 + d3;
    int incl = s;
#pragma unroll
    for (int o = 1; o < 64; o <<= 1) {
        int u = __shfl_up(incl, o, 64);
        if (lane >= o) incl += u;
    }
    if (lane == 63) s_w[w] = incl;
    __syncthreads();
    int woff = 0;
    for (int j = 0; j < 4; ++j) woff += (j < w) ? s_w[j] : 0;

    int p = blockoff[blockIdx.x] + woff + incl - s;
    int4 r;
    r.x = p;
    r.y = p + d0;
    r.z = p + d0 + d1;
    r.w = p + d0 + d1 + d2;
    if (base + 3 < N_NODES) {
        *(int4*)(rowptr + base) = r;
        *(int4*)(pos + base) = r;
    } else {
        if (base + 0 < N_NODES) { rowptr[base + 0] = r.x; pos[base + 0] = r.x; }
        if (base + 1 < N_NODES) { rowptr[base + 1] = r.y; pos[base + 1] = r.y; }
        if (base + 2 < N_NODES) { rowptr[base + 2] = r.z; pos[base + 2] = r.z; }
        if (base + 3 < N_NODES) { rowptr[base + 3] = r.w; pos[base + 3] = r.w; }
    }
}

// Scatter edges into dst-sorted order; permute src + edge_attr along with them.
__global__ void scatter_kernel(const int* __restrict__ edge_index,
                               const float* __restrict__ edge_attr,
                               int* __restrict__ pos,
                               int* __restrict__ src_perm,
                               float* __restrict__ ea_perm) {
    int e = blockIdx.x * 256 + threadIdx.x;
    if (e >= N_EDGES) return;
    int dn = edge_index[N_EDGES + e];
    int idx = atomicAdd(&pos[dn], 1);
    src_perm[idx] = edge_index[e];
    const float4* s4 = (const float4*)(edge_attr + (size_t)e * 8);
    float4* d4 = (float4*)(ea_perm + (size_t)idx * 8);
    d4[0] = s4[0];
    d4[1] = s4[1];
}

// ---------------------------------------------------------------------------
// hl = relu(LayerNorm(Y) * g + b), per-node LN over 64 channels.
__global__ __launch_bounds__(256) void ln_relu_kernel(const float* __restrict__ Y,
                                                      const float* __restrict__ g,
                                                      const float* __restrict__ b,
                                                      float* __restrict__ hl) {
    int tid = threadIdx.x;
    int w = tid >> 6, d = tid & 63;
    int n = blockIdx.x * 4 + w;
    float y = Y[(size_t)n * 64 + d];
    float s = y, sq = y * y;
#pragma unroll
    for (int offd = 32; offd >= 1; offd >>= 1) {
        s += __shfl_xor(s, offd, 64);
        sq += __shfl_xor(sq, offd, 64);
    }
    float mean = s * (1.f / 64.f);
    float var = sq * (1.f / 64.f) - mean * mean;
    float rs = rsqrtf(var + 1e-5f);
    float h = (y - mean) * rs * g[d] + b[d];
    hl[(size_t)n * 64 + d] = fmaxf(h, 0.f);
}

// ---------------------------------------------------------------------------
// Fused: softmax-aggregation over incoming edges (CSR gather, one wave/node)
// + epilogue (hl + agg) @ Wm + bm, accumulated into Y (reversible residual).
__global__ __launch_bounds__(256) void agg_epi_kernel(
    const float* __restrict__ hl, float* __restrict__ Y,
    const int* __restrict__ rowptr, const int* __restrict__ src_perm,
    const float* __restrict__ ea_perm,
    const float* __restrict__ Wcomb, const float* __restrict__ bcomb,
    const float* __restrict__ Wm, const float* __restrict__ bm) {
    __shared__ float s_wc[512];
    __shared__ float s_wm[4096];
    __shared__ float s_v[256];
    int tid = threadIdx.x;
    for (int i = tid; i < 512; i += 256) s_wc[i] = Wcomb[i];
    for (int i = tid; i < 4096; i += 256) s_wm[i] = Wm[i];
    __syncthreads();

    int w = tid >> 6, d = tid & 63;
    int n = blockIdx.x * 4 + w;

    float wc[8];
#pragma unroll
    for (int k = 0; k < 8; ++k) wc[k] = s_wc[k * 64 + d];
    float bc = bcomb[d];

    float num = 0.f, den = 0.f;
    int start = rowptr[n], end = rowptr[n + 1];
    const float4* e4 = (const float4*)ea_perm;

    int i = start;
    for (; i + 4 <= end; i += 4) {
        int s0 = src_perm[i + 0];
        int s1 = src_perm[i + 1];
        int s2 = src_perm[i + 2];
        int s3 = src_perm[i + 3];
        float h0 = hl[(size_t)s0 * 64 + d];
        float h1 = hl[(size_t)s1 * 64 + d];
        float h2 = hl[(size_t)s2 * 64 + d];
        float h3 = hl[(size_t)s3 * 64 + d];
        float4 a0 = e4[(size_t)(i + 0) * 2 + 0], a1 = e4[(size_t)(i + 0) * 2 + 1];
        float4 b0 = e4[(size_t)(i + 1) * 2 + 0], b1 = e4[(size_t)(i + 1) * 2 + 1];
        float4 c0 = e4[(size_t)(i + 2) * 2 + 0], c1 = e4[(size_t)(i + 2) * 2 + 1];
        float4 d0 = e4[(size_t)(i + 3) * 2 + 0], d1 = e4[(size_t)(i + 3) * 2 + 1];
#define DOT8(A0, A1) (bc + A0.x * wc[0] + A0.y * wc[1] + A0.z * wc[2] + A0.w * wc[3] \
                         + A1.x * wc[4] + A1.y * wc[5] + A1.z * wc[6] + A1.w * wc[7])
        float m0 = fmaxf(h0 + DOT8(a0, a1), 0.f) + 1e-7f;
        float m1 = fmaxf(h1 + DOT8(b0, b1), 0.f) + 1e-7f;
        float m2 = fmaxf(h2 + DOT8(c0, c1), 0.f) + 1e-7f;
        float m3 = fmaxf(h3 + DOT8(d0, d1), 0.f) + 1e-7f;
        float x0 = __expf(m0), x1 = __expf(m1), x2 = __expf(m2), x3 = __expf(m3);
        den += x0; num += x0 * m0;
        den += x1; num += x1 * m1;
        den += x2; num += x2 * m2;
        den += x3; num += x3 * m3;
    }
    for (; i < end; ++i) {
        int s = src_perm[i];
        float4 a0 = e4[(size_t)i * 2 + 0], a1 = e4[(size_t)i * 2 + 1];
        float h = hl[(size_t)s * 64 + d];
        float m = fmaxf(h + DOT8(a0, a1), 0.f) + 1e-7f;
        float ex = __expf(m);
        den += ex; num += ex * m;
    }
#undef DOT8

    float agg = num / (den + 1e-16f);
    float v = hl[(size_t)n * 64 + d] + agg;
    s_v[w * 64 + d] = v;  // wave-local: no block barrier needed
    float acc = bm[d];
    for (int k = 0; k < 64; ++k) acc += s_v[w * 64 + k] * s_wm[k * 64 + d];
    Y[(size_t)n * 64 + d] += acc;
}

// ---------------------------------------------------------------------------
// Final: LN over 128 -> relu -> @Wp + bp. 512 threads = 8 nodes per block;
// Wp staged in LDS once per block.
__global__ __launch_bounds__(512) void final_kernel(
    const float* __restrict__ A, const float* __restrict__ B,
    const float* __restrict__ lg, const float* __restrict__ lb,
    const float* __restrict__ Wp, const float* __restrict__ bp,
    float* __restrict__ out) {
    __shared__ float s_wp[128 * 112 + 64];  // +64 pad: dummy reads for t1>=112
    __shared__ float s_h[8][128];
    int tid = threadIdx.x;
    for (int i = tid; i < 128 * 112; i += 512) s_wp[i] = Wp[i];
    if (tid < 64) s_wp[128 * 112 + tid] = 0.f;

    int w = tid >> 6, d = tid & 63;
    int n = blockIdx.x * 8 + w;
    float v0 = A[(size_t)n * 64 + d];
    float v1 = B[(size_t)n * 64 + d];
    float s = v0 + v1, sq = v0 * v0 + v1 * v1;
#pragma unroll
    for (int offd = 32; offd >= 1; offd >>= 1) {
        s += __shfl_xor(s, offd, 64);
        sq += __shfl_xor(sq, offd, 64);
    }
    float mean = s * (1.f / 128.f);
    float var = sq * (1.f / 128.f) - mean * mean;
    float rs = rsqrtf(var + 1e-5f);
    float r0 = fmaxf((v0 - mean) * rs * lg[d] + lb[d], 0.f);
    float r1 = fmaxf((v1 - mean) * rs * lg[64 + d] + lb[64 + d], 0.f);
    s_h[w][d] = r0;
    s_h[w][64 + d] = r1;
    __syncthreads();  // covers s_wp (s_h is wave-local)

    int t0 = d, t1 = d + 64;
    float acc0 = bp[t0];
    float acc1 = (t1 < T_OUT) ? bp[t1] : 0.f;
#pragma unroll 4
    for (int c = 0; c < 128; ++c) {
        float hv = s_h[w][c];
        acc0 += hv * s_wp[c * T_OUT + t0];
        acc1 += hv * s_wp[c * T_OUT + t1];
    }
    out[(size_t)n * T_OUT + t0] = acc0;
    if (t1 < T_OUT) out[(size_t)n * T_OUT + t1] = acc1;
}

// ---------------------------------------------------------------------------
extern "C" void kernel_launch(void* const* d_in, const int* in_sizes, int n_in,
                              void* d_out, int out_size, void* d_ws, size_t ws_size,
                              hipStream_t stream) {
    const float* x            = (const float*)d_in[0];
    const int* node_index     = (const int*)d_in[1];
    const int* edge_index     = (const int*)d_in[2];
    const float* edge_attr    = (const float*)d_in[3];
    const float* node_features= (const float*)d_in[4];
    const float* W_oh         = (const float*)d_in[5];
    const float* b_oh         = (const float*)d_in[6];
    const float* W_ne         = (const float*)d_in[7];
    const float* b_ne         = (const float*)d_in[8];
    const float* W_ee         = (const float*)d_in[9];
    const float* b_ee         = (const float*)d_in[10];
    const float* ln_g         = (const float*)d_in[11];
    const float* ln_b         = (const float*)d_in[12];
    const float* We           = (const float*)d_in[13];
    const float* be           = (const float*)d_in[14];
    const float* Wm           = (const float*)d_in[15];
    const float* bm           = (const float*)d_in[16];
    const float* last_g       = (const float*)d_in[17];
    const float* last_b       = (const float*)d_in[18];
    const float* Wp           = (const float*)d_in[19];
    const float* bp           = (const float*)d_in[20];
    float* out = (float*)d_out;

    char* ws = (char*)d_ws;
    size_t off = 0;
    auto alloc = [&](size_t bytes) -> void* {
        void* p = ws + off;
        off = (off + bytes + 255) & ~(size_t)255;
        return p;
    };
    float* A        = (float*)alloc((size_t)N_NODES * 64 * 4);
    float* B        = (float*)alloc((size_t)N_NODES * 64 * 4);
    float* hl       = (float*)alloc((size_t)N_NODES * 64 * 4);
    int* deg        = (int*)alloc((size_t)N_NODES * 4);
    int* rowptr     = (int*)alloc((size_t)(N_NODES + 1) * 4);
    int* pos        = (int*)alloc((size_t)N_NODES * 4);
    int* src_perm   = (int*)alloc((size_t)N_EDGES * 4);
    float* ea_perm  = (float*)alloc((size_t)N_EDGES * 8 * 4);
    float* Wcomb    = (float*)alloc(4 * 512 * 4);
    float* bcomb    = (float*)alloc(4 * 64 * 4);
    int* blocksum   = (int*)alloc((size_t)SCAN_BLOCKS * 4);
    int* blockoff   = (int*)alloc((size_t)SCAN_BLOCKS * 4);
    (void)ws_size; (void)in_sizes; (void)n_in; (void)out_size;

    const int NB_NODE = N_NODES / 4;            // 25000
    const int NB_EDGE = (N_EDGES + 255) / 256;  // 6250

    hipMemsetAsync(deg, 0, (size_t)N_NODES * 4, stream);
    wcomb_kernel<<<4, 64, 0, stream>>>(W_ee, b_ee, We, be, Wcomb, bcomb);
    encoder_kernel<<<NB_NODE, 256, 0, stream>>>(x, node_index, node_features,
                                                W_oh, b_oh, W_ne, b_ne, A, B);
    hist_kernel<<<NB_EDGE, 256, 0, stream>>>(edge_index, deg);
    block_sum_kernel<<<SCAN_BLOCKS, 256, 0, stream>>>(deg, blocksum);
    scan_sums_kernel<<<1, 64, 0, stream>>>(blocksum, blockoff, rowptr);
    emit_kernel<<<SCAN_BLOCKS, 256, 0, stream>>>(deg, blockoff, rowptr, pos);
    scatter_kernel<<<NB_EDGE, 256, 0, stream>>>(edge_index, edge_attr, pos,
                                                src_perm, ea_perm);

    for (int lg = 0; lg < 4; ++lg) {
        const float* Yin = (lg & 1) ? A : B;
        float* Yout      = (lg & 1) ? B : A;
        ln_relu_kernel<<<NB_NODE, 256, 0, stream>>>(Yin, ln_g + lg * 64,
                                                    ln_b + lg * 64, hl);
        agg_epi_kernel<<<NB_NODE, 256, 0, stream>>>(
            hl, Yout, rowptr, src_perm, ea_perm,
            Wcomb + lg * 512, bcomb + lg * 64,
            Wm + (size_t)lg * 4096, bm + lg * 64);
    }

    final_kernel<<<N_NODES / 8, 512, 0, stream>>>(A, B, last_g, last_b, Wp, bp, out);
}

// Round 5
// 824.069 us; speedup vs baseline: 1.9914x; 1.3122x over previous
//
#include <hip/hip_runtime.h>

constexpr int N_NODES = 100000;
constexpr int N_EDGES = 1600000;
constexpr int T_OUT = 112;

constexpr int SCAN_CHUNK = 1024;
constexpr int SCAN_BLOCKS = (N_NODES + SCAN_CHUNK - 1) / SCAN_CHUNK;  // 98

typedef _Float16 h2v __attribute__((ext_vector_type(2)));

__device__ __forceinline__ float dot2h(h2v a, h2v b, float c) {
#if __has_builtin(__builtin_amdgcn_fdot2)
    return __builtin_amdgcn_fdot2(a, b, c, false);
#else
    return fmaf((float)a.x, (float)b.x, fmaf((float)a.y, (float)b.y, c));
#endif
}
__device__ __forceinline__ int pk2(float a, float b) {
    auto v = __builtin_amdgcn_cvt_pkrtz(a, b);  // __fp16 ext_vector(2)
    return __builtin_bit_cast(int, v);
}
__device__ __forceinline__ h2v b2h(int x) { return __builtin_bit_cast(h2v, x); }
__device__ __forceinline__ unsigned short f2h(float f) {
    return __builtin_bit_cast(unsigned short, (_Float16)f);
}
__device__ __forceinline__ float h2f(unsigned short u) {
    return (float)__builtin_bit_cast(_Float16, u);
}

// ---------------------------------------------------------------------------
// Wc_h2[lg][4][64] (half2-packed over input channel pairs), bcomb[lg][64].
__global__ void wcomb_kernel(const float* __restrict__ W_ee,
                             const float* __restrict__ b_ee,
                             const float* __restrict__ We,
                             const float* __restrict__ be,
                             int* __restrict__ Wc_h2,
                             float* __restrict__ bcomb) {
    int lg = blockIdx.x;
    int d = threadIdx.x;
    const float* We_ = We + (size_t)lg * 128 * 64;
    float acc[9];
#pragma unroll
    for (int k = 0; k < 9; ++k) acc[k] = 0.f;
    for (int c = 0; c < 128; ++c) {
        float wv = We_[c * 64 + d];
#pragma unroll
        for (int k = 0; k < 8; ++k) acc[k] += W_ee[k * 128 + c] * wv;
        acc[8] += b_ee[c] * wv;
    }
#pragma unroll
    for (int j = 0; j < 4; ++j)
        Wc_h2[lg * 256 + j * 64 + d] = pk2(acc[2 * j], acc[2 * j + 1]);
    bcomb[lg * 64 + d] = acc[8] + be[lg * 64 + d];
}

// ---------------------------------------------------------------------------
__global__ __launch_bounds__(256) void encoder_kernel(
    const float* __restrict__ x, const int* __restrict__ node_index,
    const float* __restrict__ node_features,
    const float* __restrict__ W_oh, const float* __restrict__ b_oh,
    const float* __restrict__ W_ne, const float* __restrict__ b_ne,
    float* __restrict__ A, float* __restrict__ B) {
    int tid = threadIdx.x;
    int w = tid >> 6, d = tid & 63;
    int n = blockIdx.x * 4 + w;

    float xf[8];
    const float* xr = x + (size_t)n * 8;
#pragma unroll
    for (int j = 0; j < 8; ++j) xf[j] = xr[j];

    float nf[16];
    int ni = node_index[n];
    const float* nfr = node_features + (size_t)ni * 8;
#pragma unroll
    for (int k = 0; k < 8; ++k) nf[k] = nfr[k];
#pragma unroll
    for (int k = 0; k < 8; ++k) {
        float acc = b_oh[k];
#pragma unroll
        for (int j = 0; j < 8; ++j) acc += xf[j] * W_oh[j * 8 + k];
        nf[8 + k] = acc;
    }
    float hA = b_ne[d], hB = b_ne[64 + d];
#pragma unroll
    for (int k = 0; k < 16; ++k) {
        hA += nf[k] * W_ne[k * 128 + d];
        hB += nf[k] * W_ne[k * 128 + 64 + d];
    }
    A[(size_t)n * 64 + d] = hA;
    B[(size_t)n * 64 + d] = hB;
}

// ---------------------------------------------------------------------------
// CSR build
__global__ void hist_kernel(const int* __restrict__ edge_index, int* __restrict__ deg) {
    int e = blockIdx.x * 256 + threadIdx.x;
    if (e < N_EDGES) atomicAdd(&deg[edge_index[N_EDGES + e]], 1);
}

__global__ __launch_bounds__(256) void block_sum_kernel(const int* __restrict__ deg,
                                                        int* __restrict__ blocksum) {
    __shared__ int s_w[4];
    int t = threadIdx.x;
    int base = blockIdx.x * SCAN_CHUNK + t * 4;
    int s = 0;
    if (base + 3 < N_NODES) {
        int4 v = *(const int4*)(deg + base);
        s = v.x + v.y + v.z + v.w;
    } else {
        for (int j = 0; j < 4; ++j)
            if (base + j < N_NODES) s += deg[base + j];
    }
#pragma unroll
    for (int o = 32; o >= 1; o >>= 1) s += __shfl_xor(s, o, 64);
    if ((t & 63) == 0) s_w[t >> 6] = s;
    __syncthreads();
    if (t == 0) blocksum[blockIdx.x] = s_w[0] + s_w[1] + s_w[2] + s_w[3];
}

__global__ __launch_bounds__(64) void scan_sums_kernel(const int* __restrict__ blocksum,
                                                       int* __restrict__ blockoff,
                                                       int* __restrict__ rowptr) {
    int t = threadIdx.x;
    int i0 = 2 * t, i1 = 2 * t + 1;
    int v0 = (i0 < SCAN_BLOCKS) ? blocksum[i0] : 0;
    int v1 = (i1 < SCAN_BLOCKS) ? blocksum[i1] : 0;
    int s = v0 + v1;
    int incl = s;
#pragma unroll
    for (int o = 1; o < 64; o <<= 1) {
        int u = __shfl_up(incl, o, 64);
        if (t >= o) incl += u;
    }
    int excl = incl - s;
    if (i0 < SCAN_BLOCKS) blockoff[i0] = excl;
    if (i1 < SCAN_BLOCKS) blockoff[i1] = excl + v0;
    if (t == 63) rowptr[N_NODES] = incl;
}

__global__ __launch_bounds__(256) void emit_kernel(const int* __restrict__ deg,
                                                   const int* __restrict__ blockoff,
                                                   int* __restrict__ rowptr,
                                                   int* __restrict__ pos) {
    __shared__ int s_w[4];
    int t = threadIdx.x;
    int w = t >> 6, lane = t & 63;
    int base = blockIdx.x * SCAN_CHUNK + t * 4;

    int d0 = 0, d1 = 0, d2 = 0, d3 = 0;
    if (base + 3 < N_NODES) {
        int4 v = *(const int4*)(deg + base);
        d0 = v.x; d1 = v.y; d2 = v.z; d3 = v.w;
    } else {
        if (base + 0 < N_NODES) d0 = deg[base + 0];
        if (base + 1 < N_NODES) d1 = deg[base + 1];
        if (base + 2 < N_NODES) d2 = deg[base + 2];
        if (base + 3 < N_NODES) d3 = deg[base + 3];
    }
    int s = d0 + d1 + d2 + d3;
    int incl = s;
#pragma unroll
    for (int o = 1; o < 64; o <<= 1) {
        int u = __shfl_up(incl, o, 64);
        if (lane >= o) incl += u;
    }
    if (lane == 63) s_w[w] = incl;
    __syncthreads();
    int woff = 0;
    for (int j = 0; j < 4; ++j) woff += (j < w) ? s_w[j] : 0;

    int p = blockoff[blockIdx.x] + woff + incl - s;
    int4 r;
    r.x = p;
    r.y = p + d0;
    r.z = p + d0 + d1;
    r.w = p + d0 + d1 + d2;
    if (base + 3 < N_NODES) {
        *(int4*)(rowptr + base) = r;
        *(int4*)(pos + base) = r;
    } else {
        if (base + 0 < N_NODES) { rowptr[base + 0] = r.x; pos[base + 0] = r.x; }
        if (base + 1 < N_NODES) { rowptr[base + 1] = r.y; pos[base + 1] = r.y; }
        if (base + 2 < N_NODES) { rowptr[base + 2] = r.z; pos[base + 2] = r.z; }
        if (base + 3 < N_NODES) { rowptr[base + 3] = r.w; pos[base + 3] = r.w; }
    }
}

// Scatter edges into dst-sorted order; edge_attr converted to packed half8.
__global__ void scatter_kernel(const int* __restrict__ edge_index,
                               const float* __restrict__ edge_attr,
                               int* __restrict__ pos,
                               int* __restrict__ src_perm,
                               int* __restrict__ ea_h) {
    int e = blockIdx.x * 256 + threadIdx.x;
    if (e >= N_EDGES) return;
    int dn = edge_index[N_EDGES + e];
    int idx = atomicAdd(&pos[dn], 1);
    src_perm[idx] = edge_index[e];
    const float4* s4 = (const float4*)(edge_attr + (size_t)e * 8);
    float4 a = s4[0], b = s4[1];
    int4 o;
    o.x = pk2(a.x, a.y);
    o.y = pk2(a.z, a.w);
    o.z = pk2(b.x, b.y);
    o.w = pk2(b.z, b.w);
    *(int4*)(ea_h + (size_t)idx * 4) = o;
}

// ---------------------------------------------------------------------------
// hl (fp16) = relu(LayerNorm(Y) * g + b)
__global__ __launch_bounds__(256) void ln_relu_kernel(const float* __restrict__ Y,
                                                      const float* __restrict__ g,
                                                      const float* __restrict__ b,
                                                      unsigned short* __restrict__ hl16) {
    int tid = threadIdx.x;
    int w = tid >> 6, d = tid & 63;
    int n = blockIdx.x * 4 + w;
    float y = Y[(size_t)n * 64 + d];
    float s = y, sq = y * y;
#pragma unroll
    for (int offd = 32; offd >= 1; offd >>= 1) {
        s += __shfl_xor(s, offd, 64);
        sq += __shfl_xor(sq, offd, 64);
    }
    float mean = s * (1.f / 64.f);
    float var = sq * (1.f / 64.f) - mean * mean;
    float rs = rsqrtf(var + 1e-5f);
    float h = (y - mean) * rs * g[d] + b[d];
    hl16[(size_t)n * 64 + d] = f2h(fmaxf(h, 0.f));
}

// ---------------------------------------------------------------------------
// Softmax aggregation (CSR gather, 1 wave/node, 8 nodes/block) + epilogue.
// Edge data fp16; dot via v_dot2_f32_f16; indices on the scalar path.
__global__ __launch_bounds__(512) void agg_epi_kernel(
    const unsigned short* __restrict__ hl16, float* __restrict__ Y,
    const int* __restrict__ rowptr, const int* __restrict__ src_perm,
    const int* __restrict__ ea_h,
    const int* __restrict__ Wc_h2, const float* __restrict__ bcomb,
    const float* __restrict__ Wm, const float* __restrict__ bm) {
    __shared__ float s_wm[4096];
    __shared__ int s_wc2[256];
    __shared__ float s_v[512];
    int tid = threadIdx.x;
    if (tid < 256) s_wc2[tid] = Wc_h2[tid];
    for (int i = tid; i < 4096; i += 512) s_wm[i] = Wm[i];
    __syncthreads();

    int w = tid >> 6, d = tid & 63;
    int n = __builtin_amdgcn_readfirstlane(blockIdx.x * 8 + w);  // wave-uniform -> SGPR

    h2v wcA = b2h(s_wc2[0 * 64 + d]);
    h2v wcB = b2h(s_wc2[1 * 64 + d]);
    h2v wcC = b2h(s_wc2[2 * 64 + d]);
    h2v wcD = b2h(s_wc2[3 * 64 + d]);
    float bc = bcomb[d];

    float num = 0.f, den = 0.f;
    int start = rowptr[n], end = rowptr[n + 1];
    const int4* ea4 = (const int4*)ea_h;

#define EDGE(U, E)                                                    \
    {                                                                 \
        float eW = bc;                                                \
        eW = dot2h(b2h(E.x), wcA, eW);                                \
        eW = dot2h(b2h(E.y), wcB, eW);                                \
        eW = dot2h(b2h(E.z), wcC, eW);                                \
        eW = dot2h(b2h(E.w), wcD, eW);                                \
        float m = fmaxf(h2f(U) + eW, 0.f) + 1e-7f;                    \
        float ex = __expf(m);                                         \
        den += ex;                                                    \
        num += ex * m;                                                \
    }

    int i = start;
    for (; i + 8 <= end; i += 8) {
        int s0 = src_perm[i + 0], s1 = src_perm[i + 1];
        int s2 = src_perm[i + 2], s3 = src_perm[i + 3];
        int s4 = src_perm[i + 4], s5 = src_perm[i + 5];
        int s6 = src_perm[i + 6], s7 = src_perm[i + 7];
        unsigned short u0 = hl16[(size_t)s0 * 64 + d];
        unsigned short u1 = hl16[(size_t)s1 * 64 + d];
        unsigned short u2 = hl16[(size_t)s2 * 64 + d];
        unsigned short u3 = hl16[(size_t)s3 * 64 + d];
        unsigned short u4 = hl16[(size_t)s4 * 64 + d];
        unsigned short u5 = hl16[(size_t)s5 * 64 + d];
        unsigned short u6 = hl16[(size_t)s6 * 64 + d];
        unsigned short u7 = hl16[(size_t)s7 * 64 + d];
        int4 e0 = ea4[i + 0], e1 = ea4[i + 1], e2 = ea4[i + 2], e3 = ea4[i + 3];
        EDGE(u0, e0) EDGE(u1, e1) EDGE(u2, e2) EDGE(u3, e3)
        int4 e4 = ea4[i + 4], e5 = ea4[i + 5], e6 = ea4[i + 6], e7 = ea4[i + 7];
        EDGE(u4, e4) EDGE(u5, e5) EDGE(u6, e6) EDGE(u7, e7)
    }
    for (; i + 4 <= end; i += 4) {
        int s0 = src_perm[i + 0], s1 = src_perm[i + 1];
        int s2 = src_perm[i + 2], s3 = src_perm[i + 3];
        unsigned short u0 = hl16[(size_t)s0 * 64 + d];
        unsigned short u1 = hl16[(size_t)s1 * 64 + d];
        unsigned short u2 = hl16[(size_t)s2 * 64 + d];
        unsigned short u3 = hl16[(size_t)s3 * 64 + d];
        int4 e0 = ea4[i + 0], e1 = ea4[i + 1], e2 = ea4[i + 2], e3 = ea4[i + 3];
        EDGE(u0, e0) EDGE(u1, e1) EDGE(u2, e2) EDGE(u3, e3)
    }
    for (; i < end; ++i) {
        int s0 = src_perm[i];
        unsigned short u0 = hl16[(size_t)s0 * 64 + d];
        int4 e0 = ea4[i];
        EDGE(u0, e0)
    }
#undef EDGE

    float agg = num / (den + 1e-16f);
    float v = h2f(hl16[(size_t)n * 64 + d]) + agg;
    s_v[w * 64 + d] = v;  // wave-local
    float acc = bm[d];
    for (int k = 0; k < 64; ++k) acc += s_v[w * 64 + k] * s_wm[k * 64 + d];
    Y[(size_t)n * 64 + d] += acc;
}

// ---------------------------------------------------------------------------
// Final: LN(128) -> relu -> @Wp + bp. 512 threads, 16 nodes/block (2 per wave);
// Wp staged in LDS once per block.
__global__ __launch_bounds__(512) void final_kernel(
    const float* __restrict__ A, const float* __restrict__ B,
    const float* __restrict__ lg, const float* __restrict__ lb,
    const float* __restrict__ Wp, const float* __restrict__ bp,
    float* __restrict__ out) {
    __shared__ float s_wp[128 * 112 + 64];
    __shared__ float s_h[8][128];
    int tid = threadIdx.x;
    for (int i = tid; i < 128 * 112; i += 512) s_wp[i] = Wp[i];
    if (tid < 64) s_wp[128 * 112 + tid] = 0.f;

    int w = tid >> 6, d = tid & 63;
    __syncthreads();  // s_wp ready (s_h is wave-local)

    for (int nn = 0; nn < 2; ++nn) {
        int n = blockIdx.x * 16 + w * 2 + nn;
        float v0 = A[(size_t)n * 64 + d];
        float v1 = B[(size_t)n * 64 + d];
        float s = v0 + v1, sq = v0 * v0 + v1 * v1;
#pragma unroll
        for (int offd = 32; offd >= 1; offd >>= 1) {
            s += __shfl_xor(s, offd, 64);
            sq += __shfl_xor(sq, offd, 64);
        }
        float mean = s * (1.f / 128.f);
        float var = sq * (1.f / 128.f) - mean * mean;
        float rs = rsqrtf(var + 1e-5f);
        float r0 = fmaxf((v0 - mean) * rs * lg[d] + lb[d], 0.f);
        float r1 = fmaxf((v1 - mean) * rs * lg[64 + d] + lb[64 + d], 0.f);
        s_h[w][d] = r0;
        s_h[w][64 + d] = r1;

        int t0 = d, t1 = d + 64;
        float acc0 = bp[t0];
        float acc1 = (t1 < T_OUT) ? bp[t1] : 0.f;
#pragma unroll 4
        for (int c = 0; c < 128; ++c) {
            float hv = s_h[w][c];
            acc0 += hv * s_wp[c * T_OUT + t0];
            acc1 += hv * s_wp[c * T_OUT + t1];
        }
        out[(size_t)n * T_OUT + t0] = acc0;
        if (t1 < T_OUT) out[(size_t)n * T_OUT + t1] = acc1;
    }
}

// ---------------------------------------------------------------------------
extern "C" void kernel_launch(void* const* d_in, const int* in_sizes, int n_in,
                              void* d_out, int out_size, void* d_ws, size_t ws_size,
                              hipStream_t stream) {
    const float* x            = (const float*)d_in[0];
    const int* node_index     = (const int*)d_in[1];
    const int* edge_index     = (const int*)d_in[2];
    const float* edge_attr    = (const float*)d_in[3];
    const float* node_features= (const float*)d_in[4];
    const float* W_oh         = (const float*)d_in[5];
    const float* b_oh         = (const float*)d_in[6];
    const float* W_ne         = (const float*)d_in[7];
    const float* b_ne         = (const float*)d_in[8];
    const float* W_ee         = (const float*)d_in[9];
    const float* b_ee         = (const float*)d_in[10];
    const float* ln_g         = (const float*)d_in[11];
    const float* ln_b         = (const float*)d_in[12];
    const float* We           = (const float*)d_in[13];
    const float* be           = (const float*)d_in[14];
    const float* Wm           = (const float*)d_in[15];
    const float* bm           = (const float*)d_in[16];
    const float* last_g       = (const float*)d_in[17];
    const float* last_b       = (const float*)d_in[18];
    const float* Wp           = (const float*)d_in[19];
    const float* bp           = (const float*)d_in[20];
    float* out = (float*)d_out;

    char* ws = (char*)d_ws;
    size_t off = 0;
    auto alloc = [&](size_t bytes) -> void* {
        void* p = ws + off;
        off = (off + bytes + 255) & ~(size_t)255;
        return p;
    };
    float* A          = (float*)alloc((size_t)N_NODES * 64 * 4);
    float* B          = (float*)alloc((size_t)N_NODES * 64 * 4);
    unsigned short* hl16 = (unsigned short*)alloc((size_t)N_NODES * 64 * 2);
    int* deg          = (int*)alloc((size_t)N_NODES * 4);
    int* rowptr       = (int*)alloc((size_t)(N_NODES + 1) * 4);
    int* pos          = (int*)alloc((size_t)N_NODES * 4);
    int* src_perm     = (int*)alloc((size_t)N_EDGES * 4);
    int* ea_h         = (int*)alloc((size_t)N_EDGES * 4 * 4);  // half8 per edge
    int* Wc_h2        = (int*)alloc(4 * 256 * 4);
    float* bcomb      = (float*)alloc(4 * 64 * 4);
    int* blocksum     = (int*)alloc((size_t)SCAN_BLOCKS * 4);
    int* blockoff     = (int*)alloc((size_t)SCAN_BLOCKS * 4);
    (void)ws_size; (void)in_sizes; (void)n_in; (void)out_size;

    const int NB_NODE = N_NODES / 4;            // 25000
    const int NB_EDGE = (N_EDGES + 255) / 256;  // 6250

    (void)hipMemsetAsync(deg, 0, (size_t)N_NODES * 4, stream);
    wcomb_kernel<<<4, 64, 0, stream>>>(W_ee, b_ee, We, be, Wc_h2, bcomb);
    encoder_kernel<<<NB_NODE, 256, 0, stream>>>(x, node_index, node_features,
                                                W_oh, b_oh, W_ne, b_ne, A, B);
    hist_kernel<<<NB_EDGE, 256, 0, stream>>>(edge_index, deg);
    block_sum_kernel<<<SCAN_BLOCKS, 256, 0, stream>>>(deg, blocksum);
    scan_sums_kernel<<<1, 64, 0, stream>>>(blocksum, blockoff, rowptr);
    emit_kernel<<<SCAN_BLOCKS, 256, 0, stream>>>(deg, blockoff, rowptr, pos);
    scatter_kernel<<<NB_EDGE, 256, 0, stream>>>(edge_index, edge_attr, pos,
                                                src_perm, ea_h);

    for (int lg4 = 0; lg4 < 4; ++lg4) {
        const float* Yin = (lg4 & 1) ? A : B;
        float* Yout      = (lg4 & 1) ? B : A;
        ln_relu_kernel<<<NB_NODE, 256, 0, stream>>>(Yin, ln_g + lg4 * 64,
                                                    ln_b + lg4 * 64, hl16);
        agg_epi_kernel<<<N_NODES / 8, 512, 0, stream>>>(
            hl16, Yout, rowptr, src_perm, ea_h,
            Wc_h2 + lg4 * 256, bcomb + lg4 * 64,
            Wm + (size_t)lg4 * 4096, bm + lg4 * 64);
    }

    final_kernel<<<N_NODES / 16, 512, 0, stream>>>(A, B, last_g, last_b, Wp, bp, out);
}

// Round 6
// 697.474 us; speedup vs baseline: 2.3529x; 1.1815x over previous
//
#include <hip/hip_runtime.h>

constexpr int N_NODES = 100000;
constexpr int N_EDGES = 1600000;
constexpr int T_OUT = 112;

constexpr int SCAN_CHUNK = 1024;
constexpr int SCAN_BLOCKS = (N_NODES + SCAN_CHUNK - 1) / SCAN_CHUNK;  // 98

typedef _Float16 h2v __attribute__((ext_vector_type(2)));
typedef _Float16 half8 __attribute__((ext_vector_type(8)));
typedef float f32x4 __attribute__((ext_vector_type(4)));

__device__ __forceinline__ float dot2h(h2v a, h2v b, float c) {
#if __has_builtin(__builtin_amdgcn_fdot2)
    return __builtin_amdgcn_fdot2(a, b, c, false);
#else
    return fmaf((float)a.x, (float)b.x, fmaf((float)a.y, (float)b.y, c));
#endif
}
__device__ __forceinline__ int pk2(float a, float b) {
    auto v = __builtin_amdgcn_cvt_pkrtz(a, b);  // __fp16 ext_vector(2)
    return __builtin_bit_cast(int, v);
}
__device__ __forceinline__ h2v b2h(int x) { return __builtin_bit_cast(h2v, x); }
__device__ __forceinline__ unsigned short f2h(float f) {
    return __builtin_bit_cast(unsigned short, (_Float16)f);
}
__device__ __forceinline__ float h2f(unsigned short u) {
    return (float)__builtin_bit_cast(_Float16, u);
}

// ---------------------------------------------------------------------------
// Wc_h2[lg][4][64] (half2-packed over input channel pairs), bcomb[lg][64].
__global__ void wcomb_kernel(const float* __restrict__ W_ee,
                             const float* __restrict__ b_ee,
                             const float* __restrict__ We,
                             const float* __restrict__ be,
                             int* __restrict__ Wc_h2,
                             float* __restrict__ bcomb) {
    int lg = blockIdx.x;
    int d = threadIdx.x;
    const float* We_ = We + (size_t)lg * 128 * 64;
    float acc[9];
#pragma unroll
    for (int k = 0; k < 9; ++k) acc[k] = 0.f;
    for (int c = 0; c < 128; ++c) {
        float wv = We_[c * 64 + d];
#pragma unroll
        for (int k = 0; k < 8; ++k) acc[k] += W_ee[k * 128 + c] * wv;
        acc[8] += b_ee[c] * wv;
    }
#pragma unroll
    for (int j = 0; j < 4; ++j)
        Wc_h2[lg * 256 + j * 64 + d] = pk2(acc[2 * j], acc[2 * j + 1]);
    bcomb[lg * 64 + d] = acc[8] + be[lg * 64 + d];
}

// ---------------------------------------------------------------------------
// Pack Wp[128][112] fp32 -> fp16 MFMA B-fragments.
// wpfrag[tile*4+m][lane][4 ints]: element j_full of lane: B[k][t],
// k = m*32 + (j_full>>2)*16 + (lane>>4)*4 + (j_full&3), t = tile*16 + (lane&15).
__global__ void wp_pack_kernel(const float* __restrict__ Wp, int* __restrict__ wpfrag) {
    int tm = blockIdx.x;  // 0..27
    int tile = tm >> 2, m = tm & 3;
    int lane = threadIdx.x;
    int g = lane >> 4, r = lane & 15;
    int t = tile * 16 + r;
    int o[4];
#pragma unroll
    for (int p = 0; p < 4; ++p) {
        int j0 = 2 * p, j1 = 2 * p + 1;
        int k0 = m * 32 + (j0 >> 2) * 16 + g * 4 + (j0 & 3);
        int k1 = m * 32 + (j1 >> 2) * 16 + g * 4 + (j1 & 3);
        o[p] = pk2(Wp[k0 * 112 + t], Wp[k1 * 112 + t]);
    }
    int4 o4; o4.x = o[0]; o4.y = o[1]; o4.z = o[2]; o4.w = o[3];
    *(int4*)(wpfrag + ((size_t)tm * 64 + lane) * 4) = o4;
}

// ---------------------------------------------------------------------------
__global__ __launch_bounds__(256) void encoder_kernel(
    const float* __restrict__ x, const int* __restrict__ node_index,
    const float* __restrict__ node_features,
    const float* __restrict__ W_oh, const float* __restrict__ b_oh,
    const float* __restrict__ W_ne, const float* __restrict__ b_ne,
    float* __restrict__ A, float* __restrict__ B) {
    int tid = threadIdx.x;
    int w = tid >> 6, d = tid & 63;
    int n = blockIdx.x * 4 + w;

    float xf[8];
    const float* xr = x + (size_t)n * 8;
#pragma unroll
    for (int j = 0; j < 8; ++j) xf[j] = xr[j];

    float nf[16];
    int ni = node_index[n];
    const float* nfr = node_features + (size_t)ni * 8;
#pragma unroll
    for (int k = 0; k < 8; ++k) nf[k] = nfr[k];
#pragma unroll
    for (int k = 0; k < 8; ++k) {
        float acc = b_oh[k];
#pragma unroll
        for (int j = 0; j < 8; ++j) acc += xf[j] * W_oh[j * 8 + k];
        nf[8 + k] = acc;
    }
    float hA = b_ne[d], hB = b_ne[64 + d];
#pragma unroll
    for (int k = 0; k < 16; ++k) {
        hA += nf[k] * W_ne[k * 128 + d];
        hB += nf[k] * W_ne[k * 128 + 64 + d];
    }
    A[(size_t)n * 64 + d] = hA;
    B[(size_t)n * 64 + d] = hB;
}

// ---------------------------------------------------------------------------
// CSR build
__global__ void hist_kernel(const int* __restrict__ edge_index, int* __restrict__ deg) {
    int e = blockIdx.x * 256 + threadIdx.x;
    if (e < N_EDGES) atomicAdd(&deg[edge_index[N_EDGES + e]], 1);
}

__global__ __launch_bounds__(256) void block_sum_kernel(const int* __restrict__ deg,
                                                        int* __restrict__ blocksum) {
    __shared__ int s_w[4];
    int t = threadIdx.x;
    int base = blockIdx.x * SCAN_CHUNK + t * 4;
    int s = 0;
    if (base + 3 < N_NODES) {
        int4 v = *(const int4*)(deg + base);
        s = v.x + v.y + v.z + v.w;
    } else {
        for (int j = 0; j < 4; ++j)
            if (base + j < N_NODES) s += deg[base + j];
    }
#pragma unroll
    for (int o = 32; o >= 1; o >>= 1) s += __shfl_xor(s, o, 64);
    if ((t & 63) == 0) s_w[t >> 6] = s;
    __syncthreads();
    if (t == 0) blocksum[blockIdx.x] = s_w[0] + s_w[1] + s_w[2] + s_w[3];
}

__global__ __launch_bounds__(64) void scan_sums_kernel(const int* __restrict__ blocksum,
                                                       int* __restrict__ blockoff,
                                                       int* __restrict__ rowptr) {
    int t = threadIdx.x;
    int i0 = 2 * t, i1 = 2 * t + 1;
    int v0 = (i0 < SCAN_BLOCKS) ? blocksum[i0] : 0;
    int v1 = (i1 < SCAN_BLOCKS) ? blocksum[i1] : 0;
    int s = v0 + v1;
    int incl = s;
#pragma unroll
    for (int o = 1; o < 64; o <<= 1) {
        int u = __shfl_up(incl, o, 64);
        if (t >= o) incl += u;
    }
    int excl = incl - s;
    if (i0 < SCAN_BLOCKS) blockoff[i0] = excl;
    if (i1 < SCAN_BLOCKS) blockoff[i1] = excl + v0;
    if (t == 63) rowptr[N_NODES] = incl;
}

__global__ __launch_bounds__(256) void emit_kernel(const int* __restrict__ deg,
                                                   const int* __restrict__ blockoff,
                                                   int* __restrict__ rowptr,
                                                   int* __restrict__ pos) {
    __shared__ int s_w[4];
    int t = threadIdx.x;
    int w = t >> 6, lane = t & 63;
    int base = blockIdx.x * SCAN_CHUNK + t * 4;

    int d0 = 0, d1 = 0, d2 = 0, d3 = 0;
    if (base + 3 < N_NODES) {
        int4 v = *(const int4*)(deg + base);
        d0 = v.x; d1 = v.y; d2 = v.z; d3 = v.w;
    } else {
        if (base + 0 < N_NODES) d0 = deg[base + 0];
        if (base + 1 < N_NODES) d1 = deg[base + 1];
        if (base + 2 < N_NODES) d2 = deg[base + 2];
        if (base + 3 < N_NODES) d3 = deg[base + 3];
    }
    int s = d0 + d1 + d2 + d3;
    int incl = s;
#pragma unroll
    for (int o = 1; o < 64; o <<= 1) {
        int u = __shfl_up(incl, o, 64);
        if (lane >= o) incl += u;
    }
    if (lane == 63) s_w[w] = incl;
    __syncthreads();
    int woff = 0;
    for (int j = 0; j < 4; ++j) woff += (j < w) ? s_w[j] : 0;

    int p = blockoff[blockIdx.x] + woff + incl - s;
    int4 r;
    r.x = p;
    r.y = p + d0;
    r.z = p + d0 + d1;
    r.w = p + d0 + d1 + d2;
    if (base + 3 < N_NODES) {
        *(int4*)(rowptr + base) = r;
        *(int4*)(pos + base) = r;
    } else {
        if (base + 0 < N_NODES) { rowptr[base + 0] = r.x; pos[base + 0] = r.x; }
        if (base + 1 < N_NODES) { rowptr[base + 1] = r.y; pos[base + 1] = r.y; }
        if (base + 2 < N_NODES) { rowptr[base + 2] = r.z; pos[base + 2] = r.z; }
        if (base + 3 < N_NODES) { rowptr[base + 3] = r.w; pos[base + 3] = r.w; }
    }
}

// Scatter edges into dst-sorted order; edge_attr converted to packed half8.
__global__ void scatter_kernel(const int* __restrict__ edge_index,
                               const float* __restrict__ edge_attr,
                               int* __restrict__ pos,
                               int* __restrict__ src_perm,
                               int* __restrict__ ea_h) {
    int e = blockIdx.x * 256 + threadIdx.x;
    if (e >= N_EDGES) return;
    int dn = edge_index[N_EDGES + e];
    int idx = atomicAdd(&pos[dn], 1);
    src_perm[idx] = edge_index[e];
    const float4* s4 = (const float4*)(edge_attr + (size_t)e * 8);
    float4 a = s4[0], b = s4[1];
    int4 o;
    o.x = pk2(a.x, a.y);
    o.y = pk2(a.z, a.w);
    o.z = pk2(b.x, b.y);
    o.w = pk2(b.z, b.w);
    *(int4*)(ea_h + (size_t)idx * 4) = o;
}

// ---------------------------------------------------------------------------
// hl (fp16) = relu(LayerNorm(Y) * g + b)
__global__ __launch_bounds__(256) void ln_relu_kernel(const float* __restrict__ Y,
                                                      const float* __restrict__ g,
                                                      const float* __restrict__ b,
                                                      unsigned short* __restrict__ hl16) {
    int tid = threadIdx.x;
    int w = tid >> 6, d = tid & 63;
    int n = blockIdx.x * 4 + w;
    float y = Y[(size_t)n * 64 + d];
    float s = y, sq = y * y;
#pragma unroll
    for (int offd = 32; offd >= 1; offd >>= 1) {
        s += __shfl_xor(s, offd, 64);
        sq += __shfl_xor(sq, offd, 64);
    }
    float mean = s * (1.f / 64.f);
    float var = sq * (1.f / 64.f) - mean * mean;
    float rs = rsqrtf(var + 1e-5f);
    float h = (y - mean) * rs * g[d] + b[d];
    hl16[(size_t)n * 64 + d] = f2h(fmaxf(h, 0.f));
}

// ---------------------------------------------------------------------------
// Softmax aggregation (CSR gather, 1 wave/node, 8 nodes/block) + epilogue.
// src indices forced to SGPR via readfirstlane (exact: i is wave-uniform).
__global__ __launch_bounds__(512) void agg_epi_kernel(
    const unsigned short* __restrict__ hl16, float* __restrict__ Y,
    const int* __restrict__ rowptr, const int* __restrict__ src_perm,
    const int* __restrict__ ea_h,
    const int* __restrict__ Wc_h2, const float* __restrict__ bcomb,
    const float* __restrict__ Wm, const float* __restrict__ bm) {
    __shared__ float s_wm[4096];
    __shared__ int s_wc2[256];
    __shared__ float s_v[512];
    int tid = threadIdx.x;
    if (tid < 256) s_wc2[tid] = Wc_h2[tid];
    for (int i = tid; i < 4096; i += 512) s_wm[i] = Wm[i];
    __syncthreads();

    int w = tid >> 6, d = tid & 63;
    int n = __builtin_amdgcn_readfirstlane(blockIdx.x * 8 + w);

    h2v wcA = b2h(s_wc2[0 * 64 + d]);
    h2v wcB = b2h(s_wc2[1 * 64 + d]);
    h2v wcC = b2h(s_wc2[2 * 64 + d]);
    h2v wcD = b2h(s_wc2[3 * 64 + d]);
    float bc = bcomb[d];

    float num = 0.f, den = 0.f;
    int start = rowptr[n], end = rowptr[n + 1];
    const int4* ea4 = (const int4*)ea_h;

#define RFL(X) __builtin_amdgcn_readfirstlane(X)
#define EDGE(U, E)                                                    \
    {                                                                 \
        float eW = bc;                                                \
        eW = dot2h(b2h(E.x), wcA, eW);                                \
        eW = dot2h(b2h(E.y), wcB, eW);                                \
        eW = dot2h(b2h(E.z), wcC, eW);                                \
        eW = dot2h(b2h(E.w), wcD, eW);                                \
        float m = fmaxf(h2f(U) + eW, 0.f) + 1e-7f;                    \
        float ex = __expf(m);                                         \
        den += ex;                                                    \
        num += ex * m;                                                \
    }

    int i = start;
    for (; i + 8 <= end; i += 8) {
        int s0 = RFL(src_perm[i + 0]), s1 = RFL(src_perm[i + 1]);
        int s2 = RFL(src_perm[i + 2]), s3 = RFL(src_perm[i + 3]);
        int s4 = RFL(src_perm[i + 4]), s5 = RFL(src_perm[i + 5]);
        int s6 = RFL(src_perm[i + 6]), s7 = RFL(src_perm[i + 7]);
        unsigned short u0 = hl16[(size_t)s0 * 64 + d];
        unsigned short u1 = hl16[(size_t)s1 * 64 + d];
        unsigned short u2 = hl16[(size_t)s2 * 64 + d];
        unsigned short u3 = hl16[(size_t)s3 * 64 + d];
        unsigned short u4 = hl16[(size_t)s4 * 64 + d];
        unsigned short u5 = hl16[(size_t)s5 * 64 + d];
        unsigned short u6 = hl16[(size_t)s6 * 64 + d];
        unsigned short u7 = hl16[(size_t)s7 * 64 + d];
        int4 e0 = ea4[i + 0], e1 = ea4[i + 1], e2 = ea4[i + 2], e3 = ea4[i + 3];
        EDGE(u0, e0) EDGE(u1, e1) EDGE(u2, e2) EDGE(u3, e3)
        int4 e4 = ea4[i + 4], e5 = ea4[i + 5], e6 = ea4[i + 6], e7 = ea4[i + 7];
        EDGE(u4, e4) EDGE(u5, e5) EDGE(u6, e6) EDGE(u7, e7)
    }
    for (; i + 4 <= end; i += 4) {
        int s0 = RFL(src_perm[i + 0]), s1 = RFL(src_perm[i + 1]);
        int s2 = RFL(src_perm[i + 2]), s3 = RFL(src_perm[i + 3]);
        unsigned short u0 = hl16[(size_t)s0 * 64 + d];
        unsigned short u1 = hl16[(size_t)s1 * 64 + d];
        unsigned short u2 = hl16[(size_t)s2 * 64 + d];
        unsigned short u3 = hl16[(size_t)s3 * 64 + d];
        int4 e0 = ea4[i + 0], e1 = ea4[i + 1], e2 = ea4[i + 2], e3 = ea4[i + 3];
        EDGE(u0, e0) EDGE(u1, e1) EDGE(u2, e2) EDGE(u3, e3)
    }
    for (; i < end; ++i) {
        int s0 = RFL(src_perm[i]);
        unsigned short u0 = hl16[(size_t)s0 * 64 + d];
        int4 e0 = ea4[i];
        EDGE(u0, e0)
    }
#undef EDGE
#undef RFL

    float agg = num / (den + 1e-16f);
    float v = h2f(hl16[(size_t)n * 64 + d]) + agg;
    s_v[w * 64 + d] = v;  // wave-local
    float acc = bm[d];
    for (int k = 0; k < 64; ++k) acc += s_v[w * 64 + k] * s_wm[k * 64 + d];
    Y[(size_t)n * 64 + d] += acc;
}

// ---------------------------------------------------------------------------
// Final: LN(128) -> relu -> MFMA GEMM @Wp + bp.
// 256 threads = 4 waves, 16 nodes/wave, no LDS, no barriers.
// Lane (r=lane&15, g=lane>>4) owns 32 channels of node r: c = kb*16+g*4+j.
__global__ __launch_bounds__(256) void final_kernel(
    const float* __restrict__ A, const float* __restrict__ B,
    const float* __restrict__ lg, const float* __restrict__ lb,
    const int* __restrict__ wpfrag, const float* __restrict__ bp,
    float* __restrict__ out) {
    int tid = threadIdx.x;
    int w = tid >> 6, lane = tid & 63;
    int g = lane >> 4, r = lane & 15;
    int nodebase = blockIdx.x * 64 + w * 16;
    if (nodebase >= N_NODES) return;  // N % 16 == 0: waves fully valid or invalid
    int n = nodebase + r;

    float4 v[8];
    const float4* A4 = (const float4*)(A + (size_t)n * 64);
    const float4* B4 = (const float4*)(B + (size_t)n * 64);
#pragma unroll
    for (int kb = 0; kb < 4; ++kb) v[kb] = A4[kb * 4 + g];
#pragma unroll
    for (int kb = 0; kb < 4; ++kb) v[4 + kb] = B4[kb * 4 + g];

    float s = 0.f, sq = 0.f;
#pragma unroll
    for (int kb = 0; kb < 8; ++kb) {
        s += v[kb].x + v[kb].y + v[kb].z + v[kb].w;
        sq += v[kb].x * v[kb].x + v[kb].y * v[kb].y
            + v[kb].z * v[kb].z + v[kb].w * v[kb].w;
    }
    s += __shfl_xor(s, 16, 64);  sq += __shfl_xor(sq, 16, 64);
    s += __shfl_xor(s, 32, 64);  sq += __shfl_xor(sq, 32, 64);
    float mean = s * (1.f / 128.f);
    float var = sq * (1.f / 128.f) - mean * mean;
    float rs = rsqrtf(var + 1e-5f);

    const float4* lg4 = (const float4*)lg;
    const float4* lb4 = (const float4*)lb;
    half8 afr[4];
#pragma unroll
    for (int kb = 0; kb < 8; ++kb) {
        float4 gv = lg4[kb * 4 + g];
        float4 bv = lb4[kb * 4 + g];
        int m = kb >> 1, e0 = (kb & 1) * 4;
        afr[m][e0 + 0] = (_Float16)fmaxf((v[kb].x - mean) * rs * gv.x + bv.x, 0.f);
        afr[m][e0 + 1] = (_Float16)fmaxf((v[kb].y - mean) * rs * gv.y + bv.y, 0.f);
        afr[m][e0 + 2] = (_Float16)fmaxf((v[kb].z - mean) * rs * gv.z + bv.z, 0.f);
        afr[m][e0 + 3] = (_Float16)fmaxf((v[kb].w - mean) * rs * gv.w + bv.w, 0.f);
    }

    const int4* wf4 = (const int4*)wpfrag;
#pragma unroll
    for (int tile = 0; tile < 7; ++tile) {
        float bias = bp[tile * 16 + r];
        f32x4 acc = {bias, bias, bias, bias};
#pragma unroll
        for (int m = 0; m < 4; ++m) {
            int4 bw = wf4[(tile * 4 + m) * 64 + lane];
            half8 bf = __builtin_bit_cast(half8, bw);
            acc = __builtin_amdgcn_mfma_f32_16x16x32_f16(afr[m], bf, acc, 0, 0, 0);
        }
#pragma unroll
        for (int q = 0; q < 4; ++q) {
            out[(size_t)(nodebase + g * 4 + q) * T_OUT + tile * 16 + r] = acc[q];
        }
    }
}

// ---------------------------------------------------------------------------
extern "C" void kernel_launch(void* const* d_in, const int* in_sizes, int n_in,
                              void* d_out, int out_size, void* d_ws, size_t ws_size,
                              hipStream_t stream) {
    const float* x            = (const float*)d_in[0];
    const int* node_index     = (const int*)d_in[1];
    const int* edge_index     = (const int*)d_in[2];
    const float* edge_attr    = (const float*)d_in[3];
    const float* node_features= (const float*)d_in[4];
    const float* W_oh         = (const float*)d_in[5];
    const float* b_oh         = (const float*)d_in[6];
    const float* W_ne         = (const float*)d_in[7];
    const float* b_ne         = (const float*)d_in[8];
    const float* W_ee         = (const float*)d_in[9];
    const float* b_ee         = (const float*)d_in[10];
    const float* ln_g         = (const float*)d_in[11];
    const float* ln_b         = (const float*)d_in[12];
    const float* We           = (const float*)d_in[13];
    const float* be           = (const float*)d_in[14];
    const float* Wm           = (const float*)d_in[15];
    const float* bm           = (const float*)d_in[16];
    const float* last_g       = (const float*)d_in[17];
    const float* last_b       = (const float*)d_in[18];
    const float* Wp           = (const float*)d_in[19];
    const float* bp           = (const float*)d_in[20];
    float* out = (float*)d_out;

    char* ws = (char*)d_ws;
    size_t off = 0;
    auto alloc = [&](size_t bytes) -> void* {
        void* p = ws + off;
        off = (off + bytes + 255) & ~(size_t)255;
        return p;
    };
    float* A          = (float*)alloc((size_t)N_NODES * 64 * 4);
    float* B          = (float*)alloc((size_t)N_NODES * 64 * 4);
    unsigned short* hl16 = (unsigned short*)alloc((size_t)N_NODES * 64 * 2);
    int* deg          = (int*)alloc((size_t)N_NODES * 4);
    int* rowptr       = (int*)alloc((size_t)(N_NODES + 1) * 4);
    int* pos          = (int*)alloc((size_t)N_NODES * 4);
    int* src_perm     = (int*)alloc((size_t)N_EDGES * 4);
    int* ea_h         = (int*)alloc((size_t)N_EDGES * 4 * 4);  // half8 per edge
    int* Wc_h2        = (int*)alloc(4 * 256 * 4);
    float* bcomb      = (float*)alloc(4 * 64 * 4);
    int* blocksum     = (int*)alloc((size_t)SCAN_BLOCKS * 4);
    int* blockoff     = (int*)alloc((size_t)SCAN_BLOCKS * 4);
    int* wpfrag       = (int*)alloc((size_t)28 * 64 * 16);     // 28 KB
    (void)ws_size; (void)in_sizes; (void)n_in; (void)out_size;

    const int NB_NODE = N_NODES / 4;            // 25000
    const int NB_EDGE = (N_EDGES + 255) / 256;  // 6250

    (void)hipMemsetAsync(deg, 0, (size_t)N_NODES * 4, stream);
    wcomb_kernel<<<4, 64, 0, stream>>>(W_ee, b_ee, We, be, Wc_h2, bcomb);
    wp_pack_kernel<<<28, 64, 0, stream>>>(Wp, wpfrag);
    encoder_kernel<<<NB_NODE, 256, 0, stream>>>(x, node_index, node_features,
                                                W_oh, b_oh, W_ne, b_ne, A, B);
    hist_kernel<<<NB_EDGE, 256, 0, stream>>>(edge_index, deg);
    block_sum_kernel<<<SCAN_BLOCKS, 256, 0, stream>>>(deg, blocksum);
    scan_sums_kernel<<<1, 64, 0, stream>>>(blocksum, blockoff, rowptr);
    emit_kernel<<<SCAN_BLOCKS, 256, 0, stream>>>(deg, blockoff, rowptr, pos);
    scatter_kernel<<<NB_EDGE, 256, 0, stream>>>(edge_index, edge_attr, pos,
                                                src_perm, ea_h);

    for (int lg4 = 0; lg4 < 4; ++lg4) {
        const float* Yin = (lg4 & 1) ? A : B;
        float* Yout      = (lg4 & 1) ? B : A;
        ln_relu_kernel<<<NB_NODE, 256, 0, stream>>>(Yin, ln_g + lg4 * 64,
                                                    ln_b + lg4 * 64, hl16);
        agg_epi_kernel<<<N_NODES / 8, 512, 0, stream>>>(
            hl16, Yout, rowptr, src_perm, ea_h,
            Wc_h2 + lg4 * 256, bcomb + lg4 * 64,
            Wm + (size_t)lg4 * 4096, bm + lg4 * 64);
    }

    final_kernel<<<(N_NODES + 63) / 64, 256, 0, stream>>>(
        A, B, last_g, last_b, wpfrag, bp, out);
}